// Round 3
// baseline (3275.458 us; speedup 1.0000x reference)
//
#include <hip/hip_runtime.h>

#define DB 512
#define DT 26
#define DF 2048
#define DH 1024
#define DG 4096
#define DC 22

typedef unsigned short u16;
typedef u16 u16x8 __attribute__((ext_vector_type(8)));
typedef __bf16 bf16x8 __attribute__((ext_vector_type(8)));
typedef float f32x4 __attribute__((ext_vector_type(4)));

__device__ __forceinline__ float sigm(float x) { return 1.f / (1.f + __expf(-x)); }

// fp32 -> bf16 (RNE)
__device__ __forceinline__ u16 f2b(float v) {
  unsigned u = __float_as_uint(v);
  return (u16)((u + 0x7FFFu + ((u >> 16) & 1u)) >> 16);
}
__device__ __forceinline__ float b2f(u16 h) {
  return __uint_as_float(((unsigned)h) << 16);
}
__device__ __forceinline__ void store_b4(u16* __restrict__ d, size_t o, float4 v) {
  ushort4 s;
  s.x = f2b(v.x); s.y = f2b(v.y); s.z = f2b(v.z); s.w = f2b(v.w);
  *(ushort4*)(d + o) = s;
}

// C[M,N] = A @ B^T + bias.  A = [A1 (k<K1) | A2 (k>=K1)] bf16, B[N,K] row-stride ldb.
// OUTBF: 0 -> fp32 C, 1 -> bf16 C.  M%64==0, N%128==0, K%64==0, K1%64==0, grid%8==0.
// 256 threads = 4 waves (2x2), wave tile 32x64, block tile 64x128, BK=64.
template <int OUTBF>
__global__ __launch_bounds__(256) void gemm_bt(
    const u16* __restrict__ A1, long lda1, int K1,
    const u16* __restrict__ A2, long lda2,
    const u16* __restrict__ B, long ldb, const float* __restrict__ bias,
    void* __restrict__ Cp, long ldc, int M, int N, int K)
{
  constexpr int LR = 72;                       // padded LDS row (u16): 64 + 8
  __shared__ __align__(16) u16 sA[64 * LR];
  __shared__ __align__(16) u16 sB[128 * LR];
  const int tid = threadIdx.x, lane = tid & 63;
  const int wid = tid >> 6, wm = wid >> 1, wn = wid & 1;   // 2x2 waves
  const int nbm = M >> 6;
  const int cpx = gridDim.x >> 3;              // XCD-chunked swizzle (grid%8==0)
  const int swz = (blockIdx.x & 7) * cpx + (blockIdx.x >> 3);
  const int bn = swz / nbm, bm = swz % nbm;
  const size_t m0 = (size_t)bm << 6, n0 = (size_t)bn << 7;

  const int row = tid >> 3, c8 = tid & 7;      // staging: row, 16B-chunk within row
  u16x8 ra[2], rb[4];

  auto loadA = [&](int k0) {
    const u16* p; long lda; int kk;
    if (k0 < K1) { p = A1; lda = lda1; kk = k0; }
    else         { p = A2; lda = lda2; kk = k0 - K1; }
#pragma unroll
    for (int r = 0; r < 2; ++r)
      ra[r] = *(const u16x8*)(p + (m0 + row + r * 32) * (size_t)lda + (size_t)(kk + c8 * 8));
  };
  auto loadB = [&](int k0) {
#pragma unroll
    for (int r = 0; r < 4; ++r)
      rb[r] = *(const u16x8*)(B + (n0 + row + r * 32) * (size_t)ldb + (size_t)(k0 + c8 * 8));
  };
  loadA(0);
  loadB(0);

  f32x4 acc[2][4] = {};
  for (int k0 = 0; k0 < K; k0 += 64) {
    __syncthreads();                           // consumers of prev tile done
#pragma unroll
    for (int r = 0; r < 2; ++r) *(u16x8*)(sA + (row + r * 32) * LR + c8 * 8) = ra[r];
#pragma unroll
    for (int r = 0; r < 4; ++r) *(u16x8*)(sB + (row + r * 32) * LR + c8 * 8) = rb[r];
    __syncthreads();
    if (k0 + 64 < K) { loadA(k0 + 64); loadB(k0 + 64); }   // prefetch next tile
#pragma unroll
    for (int ks = 0; ks < 2; ++ks) {
      const int ko = ks * 32 + (lane >> 4) * 8;
      bf16x8 af[2], bfr[4];
#pragma unroll
      for (int mi = 0; mi < 2; ++mi)
        af[mi] = *(const bf16x8*)(sA + ((wm << 5) + (mi << 4) + (lane & 15)) * LR + ko);
#pragma unroll
      for (int ni = 0; ni < 4; ++ni)
        bfr[ni] = *(const bf16x8*)(sB + ((wn << 6) + (ni << 4) + (lane & 15)) * LR + ko);
#pragma unroll
      for (int mi = 0; mi < 2; ++mi)
#pragma unroll
        for (int ni = 0; ni < 4; ++ni)
          acc[mi][ni] = __builtin_amdgcn_mfma_f32_16x16x32_bf16(af[mi], bfr[ni], acc[mi][ni], 0, 0, 0);
    }
  }

#pragma unroll
  for (int mi = 0; mi < 2; ++mi) {
    const int row0 = (wm << 5) + (mi << 4) + ((lane >> 4) << 2);
#pragma unroll
    for (int ni = 0; ni < 4; ++ni) {
      const size_t gn = n0 + (size_t)((wn << 6) + (ni << 4) + (lane & 15));
      const float bv = bias[gn];
#pragma unroll
      for (int r = 0; r < 4; ++r) {
        const size_t gm = m0 + (size_t)(row0 + r);
        const float v = acc[mi][ni][r] + bv;
        if (OUTBF) ((u16*)Cp)[gm * (size_t)ldc + gn] = f2b(v);
        else       ((float*)Cp)[gm * (size_t)ldc + gn] = v;
      }
    }
  }
}

// flat fp32 -> bf16
__global__ __launch_bounds__(256) void cvt4_kernel(const float* __restrict__ src,
    u16* __restrict__ dst, int n4) {
  for (int i = blockIdx.x * 256 + threadIdx.x; i < n4; i += gridDim.x * 256) {
    float4 v = *(const float4*)(src + (size_t)i * 4);
    store_b4(dst, (size_t)i * 4, v);
  }
}

// strided fp32 matrix [rows x ld_src] -> bf16 dst at column offset dcol0 (row stride ld_dst)
__global__ __launch_bounds__(256) void cvt_strided_kernel(const float* __restrict__ src,
    int ld_src, int rows, int cols4, u16* __restrict__ dst, int ld_dst, int dcol0) {
  const int total = rows * cols4;
  for (int i = blockIdx.x * 256 + threadIdx.x; i < total; i += gridDim.x * 256) {
    const int r = i / cols4, c4 = i - r * cols4;
    float4 v = *(const float4*)(src + (size_t)r * ld_src + (size_t)c4 * 4);
    store_b4(dst, (size_t)r * ld_dst + dcol0 + (size_t)c4 * 4, v);
  }
}

__global__ void bias_sum_kernel(const float* __restrict__ a, const float* __restrict__ b,
                                float* __restrict__ o, int n) {
  int i = blockIdx.x * 256 + threadIdx.x;
  if (i < n) o[i] = a[i] + b[i];
}

__device__ __forceinline__ void cell4(float4 gi, float4 gf, float4 gg, float4 go,
                                      float4 cp, float4& cn, float4& hn) {
  cn.x = sigm(gf.x) * cp.x + sigm(gi.x) * tanhf(gg.x);  hn.x = sigm(go.x) * tanhf(cn.x);
  cn.y = sigm(gf.y) * cp.y + sigm(gi.y) * tanhf(gg.y);  hn.y = sigm(go.y) * tanhf(cn.y);
  cn.z = sigm(gf.z) * cp.z + sigm(gi.z) * tanhf(gg.z);  hn.z = sigm(go.z) * tanhf(cn.z);
  cn.w = sigm(gf.w) * cp.w + sigm(gi.w) * tanhf(gg.w);  hn.w = sigm(go.w) * tanhf(cn.w);
}

__global__ __launch_bounds__(256) void enc_cell(const float* __restrict__ gates,
    float* __restrict__ cst, u16* __restrict__ Hb, int t, int first) {
  int idx = blockIdx.x * 256 + threadIdx.x;    // B*H/4 threads
  int b = idx >> 8, q = idx & 255;
  size_t g0 = ((size_t)b << 12) + ((size_t)q << 2);
  float4 gi = *(const float4*)(gates + g0);
  float4 gf = *(const float4*)(gates + g0 + 1024);
  float4 gg = *(const float4*)(gates + g0 + 2048);
  float4 go = *(const float4*)(gates + g0 + 3072);
  size_t ci = ((size_t)b << 10) + ((size_t)q << 2);
  float4 cp = first ? make_float4(0, 0, 0, 0) : *(const float4*)(cst + ci);
  float4 cn, hn;
  cell4(gi, gf, gg, go, cp, cn, hn);
  *(float4*)(cst + ci) = cn;
  store_b4(Hb, (size_t)t * DB * DH + ci, hn);
}

// one block per batch row: attention over 26 encoder states (projH bf16)
__global__ __launch_bounds__(256) void attn_kernel(const u16* __restrict__ projH,
    const float* __restrict__ decH, u16* __restrict__ Zb) {
  const int b = blockIdx.x, tid = threadIdx.x, lane = tid & 63, wid = tid >> 6;
  __shared__ float red[DT][4];
  __shared__ float wgt[DT];
  const float4 dh = *(const float4*)(decH + ((size_t)b << 10) + tid * 4);
  float ph[DT][4];
  float p[DT];
#pragma unroll
  for (int t = 0; t < DT; ++t) {
    ushort4 pv = *(const ushort4*)(projH + (((size_t)t * DB + b) << 10) + tid * 4);
    ph[t][0] = b2f(pv.x); ph[t][1] = b2f(pv.y); ph[t][2] = b2f(pv.z); ph[t][3] = b2f(pv.w);
    p[t] = dh.x * ph[t][0] + dh.y * ph[t][1] + dh.z * ph[t][2] + dh.w * ph[t][3];
  }
#pragma unroll
  for (int t = 0; t < DT; ++t) {
#pragma unroll
    for (int off = 32; off; off >>= 1) p[t] += __shfl_xor(p[t], off);
    if (lane == 0) red[t][wid] = p[t];
  }
  __syncthreads();
  if (tid == 0) {
    float lg[DT];
    float mx = -1e30f;
#pragma unroll
    for (int t = 0; t < DT; ++t) {
      lg[t] = (red[t][0] + red[t][1] + red[t][2] + red[t][3]) * 0.03125f;
      mx = fmaxf(mx, lg[t]);
    }
    float s = 0.f;
#pragma unroll
    for (int t = 0; t < DT; ++t) { lg[t] = __expf(lg[t] - mx); s += lg[t]; }
    float inv = 1.f / s;
#pragma unroll
    for (int t = 0; t < DT; ++t) wgt[t] = lg[t] * inv;
  }
  __syncthreads();
  float4 a = make_float4(0, 0, 0, 0);
#pragma unroll
  for (int t = 0; t < DT; ++t) {
    const float w = wgt[t];
    a.x += w * ph[t][0]; a.y += w * ph[t][1]; a.z += w * ph[t][2]; a.w += w * ph[t][3];
  }
  store_b4(Zb, ((size_t)b << 11) + tid * 4, a);
}

// one block per batch row: LSTM cell + classifier head
__global__ __launch_bounds__(256) void dec_cell_cls(const float* __restrict__ gates,
    float* __restrict__ cst, float* __restrict__ hst, u16* __restrict__ Zb,
    const float* __restrict__ clsW, const float* __restrict__ clsb,
    float* __restrict__ out, int t, int first) {
  const int b = blockIdx.x, tid = threadIdx.x, lane = tid & 63, wid = tid >> 6;
  size_t g0 = ((size_t)b << 12) + ((size_t)tid << 2);
  float4 gi = *(const float4*)(gates + g0);
  float4 gf = *(const float4*)(gates + g0 + 1024);
  float4 gg = *(const float4*)(gates + g0 + 2048);
  float4 go = *(const float4*)(gates + g0 + 3072);
  size_t ci = ((size_t)b << 10) + ((size_t)tid << 2);
  float4 cp = first ? make_float4(0, 0, 0, 0) : *(const float4*)(cst + ci);
  float4 cn, hn;
  cell4(gi, gf, gg, go, cp, cn, hn);
  *(float4*)(cst + ci) = cn;
  *(float4*)(hst + ci) = hn;
  store_b4(Zb, ((size_t)b << 11) + 1024 + ((size_t)tid << 2), hn);

  float acc[DC];
#pragma unroll
  for (int c = 0; c < DC; ++c) {
    const float4 w = *(const float4*)(clsW + ((size_t)c << 10) + ((size_t)tid << 2));
    acc[c] = hn.x * w.x + hn.y * w.y + hn.z * w.z + hn.w * w.w;
  }
  __shared__ float red[DC][4];
#pragma unroll
  for (int c = 0; c < DC; ++c) {
    float v = acc[c];
#pragma unroll
    for (int off = 32; off; off >>= 1) v += __shfl_xor(v, off);
    if (lane == 0) red[c][wid] = v;
  }
  __syncthreads();
  if (tid < DC) {
    out[((size_t)b * DT + t) * DC + tid] =
        red[tid][0] + red[tid][1] + red[tid][2] + red[tid][3] + clsb[tid];
  }
}

extern "C" void kernel_launch(void* const* d_in, const int* in_sizes, int n_in,
                              void* d_out, int out_size, void* d_ws, size_t ws_size,
                              hipStream_t stream) {
  const float* x    = (const float*)d_in[0];
  const float* eWih = (const float*)d_in[1];
  const float* eWhh = (const float*)d_in[2];
  const float* ebih = (const float*)d_in[3];
  const float* ebhh = (const float*)d_in[4];
  const float* pW   = (const float*)d_in[5];
  const float* pb   = (const float*)d_in[6];
  const float* dWih = (const float*)d_in[7];
  const float* dWhh = (const float*)d_in[8];
  const float* dbih = (const float*)d_in[9];
  const float* dbhh = (const float*)d_in[10];
  const float* clsW = (const float*)d_in[11];
  const float* clsb = (const float*)d_in[12];
  float* out = (float*)d_out;

  char* p = (char*)d_ws;
  auto alloc = [&](size_t bytes) -> void* {
    char* r = p; p += (bytes + 255) & ~(size_t)255; return (void*)r;
  };
  u16* Xb  = (u16*)alloc((size_t)DB * DT * DF * 2);          // 54.5 MB
  u16* eW  = (u16*)alloc((size_t)DG * 3072 * 2);             // 25.2 MB
  u16* dW  = (u16*)alloc((size_t)DG * 4096 * 2);             // 33.6 MB
  u16* pWb = (u16*)alloc((size_t)DH * DH * 2);               //  2.1 MB
  u16* Hb  = (u16*)alloc((size_t)DT * DB * DH * 2);          // 27.3 MB
  u16* Hz  = (u16*)alloc((size_t)DB * DH * 2);               //  1.0 MB (zeros)
  u16* projHb = (u16*)alloc((size_t)DT * DB * DH * 2);       // 27.3 MB
  float* gates = (float*)alloc((size_t)DB * DG * 4);         //  8.4 MB
  u16* Zb  = (u16*)alloc((size_t)DB * 2048 * 2);             //  2.1 MB
  float* dHs = (float*)alloc((size_t)DB * DH * 4);
  float* dCs = (float*)alloc((size_t)DB * DH * 4);
  float* eCs = (float*)alloc((size_t)DB * DH * 4);
  float* ebs = (float*)alloc(DG * 4);
  float* dbs = (float*)alloc(DG * 4);
  // total ~186 MB

  // ---- pack inputs to bf16, fuse weight matrices ----
  cvt4_kernel<<<2048, 256, 0, stream>>>(x, Xb, (int)((size_t)DB * DT * DF / 4));
  // encW = [Wih | Whh]  (ld 3072)
  cvt_strided_kernel<<<2048, 256, 0, stream>>>(eWih, DF, DG, DF / 4, eW, 3072, 0);
  cvt_strided_kernel<<<2048, 256, 0, stream>>>(eWhh, DH, DG, DH / 4, eW, 3072, 2048);
  // decW = [Wih_x | Wih_attn | Whh]  (ld 4096)
  cvt_strided_kernel<<<2048, 256, 0, stream>>>(dWih, 3072, DG, 3072 / 4, dW, 4096, 0);
  cvt_strided_kernel<<<2048, 256, 0, stream>>>(dWhh, DH, DG, DH / 4, dW, 4096, 3072);
  cvt4_kernel<<<1024, 256, 0, stream>>>(pW, pWb, DH * DH / 4);
  bias_sum_kernel<<<16, 256, 0, stream>>>(ebih, ebhh, ebs, DG);
  bias_sum_kernel<<<16, 256, 0, stream>>>(dbih, dbhh, dbs, DG);
  hipMemsetAsync(Hz, 0, (size_t)DB * DH * 2, stream);
  hipMemsetAsync(Zb, 0, (size_t)DB * 2048 * 2, stream);
  hipMemsetAsync(dHs, 0, (size_t)DB * DH * 4, stream);

  // ---- encoder: gates = [x_t | h_{t-1}] @ eW^T + ebs ----
  for (int t = 0; t < DT; ++t) {
    gemm_bt<0><<<256, 256, 0, stream>>>(
        Xb + (size_t)t * DF, (long)DT * DF, 2048,
        (t == 0) ? Hz : (Hb + (size_t)(t - 1) * DB * DH), (long)DH,
        eW, 3072, ebs, gates, (long)DG, DB, DG, 3072);
    enc_cell<<<512, 256, 0, stream>>>(gates, eCs, Hb, t, t == 0);
  }

  // ---- projection of all encoder states (bf16 out) ----
  gemm_bt<1><<<1664, 256, 0, stream>>>(
      Hb, (long)DH, DH, Hb, (long)DH,
      pWb, DH, pb, projHb, (long)DH, DT * DB, DH, DH);

  // ---- decoder: gates = [x_t | attn | dec_h] @ dW^T + dbs ----
  for (int t = 0; t < DT; ++t) {
    attn_kernel<<<DB, 256, 0, stream>>>(projHb, dHs, Zb);
    gemm_bt<0><<<256, 256, 0, stream>>>(
        Xb + (size_t)t * DF, (long)DT * DF, 2048,
        Zb, (long)2048,
        dW, 4096, dbs, gates, (long)DG, DB, DG, 4096);
    dec_cell_cls<<<DB, 256, 0, stream>>>(gates, dCs, dHs, Zb, clsW, clsb, out, t, t == 0);
  }
}

// Round 4
// 2174.185 us; speedup vs baseline: 1.5065x; 1.5065x over previous
//
#include <hip/hip_runtime.h>

#define DB 512
#define DT 26
#define DF 2048
#define DH 1024
#define DG 4096
#define DC 22

typedef unsigned short u16;
typedef u16 u16x8 __attribute__((ext_vector_type(8)));
typedef __bf16 bf16x8 __attribute__((ext_vector_type(8)));
typedef float f32x4 __attribute__((ext_vector_type(4)));

__device__ __forceinline__ float sigm(float x) { return 1.f / (1.f + __expf(-x)); }

__device__ __forceinline__ u16 f2b(float v) {
  unsigned u = __float_as_uint(v);
  return (u16)((u + 0x7FFFu + ((u >> 16) & 1u)) >> 16);
}
__device__ __forceinline__ float b2f(u16 h) {
  return __uint_as_float(((unsigned)h) << 16);
}
__device__ __forceinline__ void store_b4(u16* __restrict__ d, size_t o, float4 v) {
  ushort4 s;
  s.x = f2b(v.x); s.y = f2b(v.y); s.z = f2b(v.z); s.w = f2b(v.w);
  *(ushort4*)(d + o) = s;
}

// ---------- proven round-3 GEMM (used for the 3 big parallel GEMMs) ----------
// C[M,N] = A @ B^T + bias.  A = [A1 (k<K1) | A2 (k>=K1)] bf16, B[N,K] row-stride ldb.
template <int OUTBF>
__global__ __launch_bounds__(256) void gemm_bt(
    const u16* __restrict__ A1, long lda1, int K1,
    const u16* __restrict__ A2, long lda2,
    const u16* __restrict__ B, long ldb, const float* __restrict__ bias,
    void* __restrict__ Cp, long ldc, int M, int N, int K)
{
  constexpr int LR = 72;
  __shared__ __align__(16) u16 sA[64 * LR];
  __shared__ __align__(16) u16 sB[128 * LR];
  const int tid = threadIdx.x, lane = tid & 63;
  const int wid = tid >> 6, wm = wid >> 1, wn = wid & 1;
  const int nbm = M >> 6;
  const int cpx = gridDim.x >> 3;
  const int swz = (blockIdx.x & 7) * cpx + (blockIdx.x >> 3);
  const int bn = swz / nbm, bm = swz % nbm;
  const size_t m0 = (size_t)bm << 6, n0 = (size_t)bn << 7;

  const int row = tid >> 3, c8 = tid & 7;
  u16x8 ra[2], rb[4];

  auto loadA = [&](int k0) {
    const u16* p; long lda; int kk;
    if (k0 < K1) { p = A1; lda = lda1; kk = k0; }
    else         { p = A2; lda = lda2; kk = k0 - K1; }
#pragma unroll
    for (int r = 0; r < 2; ++r)
      ra[r] = *(const u16x8*)(p + (m0 + row + r * 32) * (size_t)lda + (size_t)(kk + c8 * 8));
  };
  auto loadB = [&](int k0) {
#pragma unroll
    for (int r = 0; r < 4; ++r)
      rb[r] = *(const u16x8*)(B + (n0 + row + r * 32) * (size_t)ldb + (size_t)(k0 + c8 * 8));
  };
  loadA(0);
  loadB(0);

  f32x4 acc[2][4] = {};
  for (int k0 = 0; k0 < K; k0 += 64) {
    __syncthreads();
#pragma unroll
    for (int r = 0; r < 2; ++r) *(u16x8*)(sA + (row + r * 32) * LR + c8 * 8) = ra[r];
#pragma unroll
    for (int r = 0; r < 4; ++r) *(u16x8*)(sB + (row + r * 32) * LR + c8 * 8) = rb[r];
    __syncthreads();
    if (k0 + 64 < K) { loadA(k0 + 64); loadB(k0 + 64); }
#pragma unroll
    for (int ks = 0; ks < 2; ++ks) {
      const int ko = ks * 32 + (lane >> 4) * 8;
      bf16x8 af[2], bfr[4];
#pragma unroll
      for (int mi = 0; mi < 2; ++mi)
        af[mi] = *(const bf16x8*)(sA + ((wm << 5) + (mi << 4) + (lane & 15)) * LR + ko);
#pragma unroll
      for (int ni = 0; ni < 4; ++ni)
        bfr[ni] = *(const bf16x8*)(sB + ((wn << 6) + (ni << 4) + (lane & 15)) * LR + ko);
#pragma unroll
      for (int mi = 0; mi < 2; ++mi)
#pragma unroll
        for (int ni = 0; ni < 4; ++ni)
          acc[mi][ni] = __builtin_amdgcn_mfma_f32_16x16x32_bf16(af[mi], bfr[ni], acc[mi][ni], 0, 0, 0);
    }
  }

#pragma unroll
  for (int mi = 0; mi < 2; ++mi) {
    const int row0 = (wm << 5) + (mi << 4) + ((lane >> 4) << 2);
#pragma unroll
    for (int ni = 0; ni < 4; ++ni) {
      const size_t gn = n0 + (size_t)((wn << 6) + (ni << 4) + (lane & 15));
      const float bv = bias[gn];
#pragma unroll
      for (int r = 0; r < 4; ++r) {
        const size_t gm = m0 + (size_t)(row0 + r);
        const float v = acc[mi][ni][r] + bv;
        if (OUTBF) ((u16*)Cp)[gm * (size_t)ldc + gn] = f2b(v);
        else       ((float*)Cp)[gm * (size_t)ldc + gn] = v;
      }
    }
  }
}

// ---------- fused per-step GEMM + LSTM cell ----------
// gates[512,4096] = A @ B^T + xg  (all in permuted gate order n' = ((h>>4)<<6)|(g<<4)|(h&15))
// then cell update in-lane; h_new written bf16 to hout (enc: [512,1024]; dec: Z[:,1024:2048]).
// 512 threads = 8 waves (4m x 2n), wave tile 16x64, block tile 64x128, BK=64. grid = 256.
template <int DEC>
__global__ __launch_bounds__(512) void step_gemm(
    const u16* __restrict__ A, const u16* __restrict__ B,
    const u16* __restrict__ xg, long ldxg, float* __restrict__ cst,
    u16* __restrict__ hout, int K, int first)
{
  constexpr int LR = 72;
  __shared__ __align__(16) u16 sA[64 * LR];
  __shared__ __align__(16) u16 sB[128 * LR];
  const int tid = threadIdx.x, lane = tid & 63;
  const int wid = tid >> 6, wm = wid >> 1, wn = wid & 1;   // 4m x 2n
  const int cpx = gridDim.x >> 3;              // 32
  const int swz = (blockIdx.x & 7) * cpx + (blockIdx.x >> 3);
  const int bn = swz >> 3, bm = swz & 7;       // nbm = 8 (M=512)
  const size_t m0 = (size_t)bm << 6, n0 = (size_t)bn << 7;

  const int row = tid >> 3, c8 = tid & 7;      // 512 thr: A 64rows x 8chunks; B 2x
  u16x8 ra, rb[2];
  auto loadA = [&](int k0) {
    ra = *(const u16x8*)(A + (m0 + row) * (size_t)K + (size_t)(k0 + c8 * 8));
  };
  auto loadB = [&](int k0) {
#pragma unroll
    for (int r = 0; r < 2; ++r)
      rb[r] = *(const u16x8*)(B + (n0 + row + r * 64) * (size_t)K + (size_t)(k0 + c8 * 8));
  };
  loadA(0);
  loadB(0);

  f32x4 acc[4] = {};
  for (int k0 = 0; k0 < K; k0 += 64) {
    __syncthreads();
    *(u16x8*)(sA + row * LR + c8 * 8) = ra;
#pragma unroll
    for (int r = 0; r < 2; ++r) *(u16x8*)(sB + (row + r * 64) * LR + c8 * 8) = rb[r];
    __syncthreads();
    if (k0 + 64 < K) { loadA(k0 + 64); loadB(k0 + 64); }
#pragma unroll
    for (int ks = 0; ks < 2; ++ks) {
      const int ko = ks * 32 + (lane >> 4) * 8;
      bf16x8 af, bfr[4];
      af = *(const bf16x8*)(sA + ((wm << 4) + (lane & 15)) * LR + ko);
#pragma unroll
      for (int ni = 0; ni < 4; ++ni)
        bfr[ni] = *(const bf16x8*)(sB + ((wn << 6) + (ni << 4) + (lane & 15)) * LR + ko);
#pragma unroll
      for (int ni = 0; ni < 4; ++ni)
        acc[ni] = __builtin_amdgcn_mfma_f32_16x16x32_bf16(af, bfr[ni], acc[ni], 0, 0, 0);
    }
  }

  // epilogue: lane holds gates ni=0..3 (i,f,g,o) of unit h for 4 rows
  const int l = lane & 15;
  const int hg = (bn << 5) + (wn << 4) + l;    // global h unit
  const int row0 = (wm << 4) + ((lane >> 4) << 2);
#pragma unroll
  for (int r = 0; r < 4; ++r) {
    const int gm = (int)m0 + row0 + r;         // batch row
    const u16* xr = xg + (size_t)gm * ldxg + n0 + (wn << 6) + l;
    const float gi = acc[0][r] + b2f(xr[0]);
    const float gf = acc[1][r] + b2f(xr[16]);
    const float gg = acc[2][r] + b2f(xr[32]);
    const float go = acc[3][r] + b2f(xr[48]);
    const size_t ch = ((size_t)gm << 10) + hg;
    const float cp = first ? 0.f : cst[ch];
    const float cn = sigm(gf) * cp + sigm(gi) * tanhf(gg);
    const float hn = sigm(go) * tanhf(cn);
    cst[ch] = cn;
    if (DEC) hout[((size_t)gm << 11) + 1024 + hg] = f2b(hn);
    else     hout[((size_t)gm << 10) + hg] = f2b(hn);
  }
}

// ---------- packers ----------
__global__ __launch_bounds__(256) void cvt4_kernel(const float* __restrict__ src,
    u16* __restrict__ dst, int n4) {
  for (int i = blockIdx.x * 256 + threadIdx.x; i < n4; i += gridDim.x * 256) {
    float4 v = *(const float4*)(src + (size_t)i * 4);
    store_b4(dst, (size_t)i * 4, v);
  }
}

// weight pack with gate-interleave row permutation:
// dst row n' <- src row n = g*1024+h, where g=(n'>>4)&3, h=((n'>>6)<<4)|(n'&15)
__global__ __launch_bounds__(256) void pack_perm_kernel(const float* __restrict__ src,
    long ld_src, long scol, int cols4, u16* __restrict__ dst, long ld_dst, long dcol) {
  const int total = DG * cols4;
  for (int i = blockIdx.x * 256 + threadIdx.x; i < total; i += gridDim.x * 256) {
    const int np = i / cols4, c4 = i - np * cols4;
    const int g = (np >> 4) & 3, h = ((np >> 6) << 4) | (np & 15);
    const int n = g * 1024 + h;
    float4 v = *(const float4*)(src + (size_t)n * ld_src + scol + (size_t)c4 * 4);
    store_b4(dst, (size_t)np * ld_dst + dcol + (size_t)c4 * 4, v);
  }
}

__global__ void pack_bias_perm_kernel(const float* __restrict__ a,
    const float* __restrict__ b, float* __restrict__ o) {
  int np = blockIdx.x * 256 + threadIdx.x;
  if (np < DG) {
    const int g = (np >> 4) & 3, h = ((np >> 6) << 4) | (np & 15);
    const int n = g * 1024 + h;
    o[np] = a[n] + b[n];
  }
}

// ---------- fused attention(t) + classifier(t-1); one block per batch row ----------
template <int DO_ATTN>
__global__ __launch_bounds__(256) void attn_cls_kernel(
    const u16* __restrict__ projH, const u16* __restrict__ Zr, u16* __restrict__ Zw,
    const float* __restrict__ clsW, const float* __restrict__ clsb,
    float* __restrict__ out, int do_cls, int tprev)
{
  const int b = blockIdx.x, tid = threadIdx.x, lane = tid & 63, wid = tid >> 6;
  __shared__ float redc[DC][4];
  __shared__ float red[DT][4];
  __shared__ float wgt[DT];

  ushort4 hz = *(const ushort4*)(Zr + ((size_t)b << 11) + 1024 + tid * 4);
  float4 hv = make_float4(b2f(hz.x), b2f(hz.y), b2f(hz.z), b2f(hz.w));

  if (do_cls) {                                 // classifier for h_{t-1}
    float acc[DC];
#pragma unroll
    for (int c = 0; c < DC; ++c) {
      const float4 w = *(const float4*)(clsW + ((size_t)c << 10) + tid * 4);
      acc[c] = hv.x * w.x + hv.y * w.y + hv.z * w.z + hv.w * w.w;
    }
#pragma unroll
    for (int c = 0; c < DC; ++c) {
      float v = acc[c];
#pragma unroll
      for (int off = 32; off; off >>= 1) v += __shfl_xor(v, off);
      if (lane == 0) redc[c][wid] = v;
    }
  }

  if (DO_ATTN) {
    float ph[DT][4];
    float p[DT];
#pragma unroll
    for (int t = 0; t < DT; ++t) {
      ushort4 pv = *(const ushort4*)(projH + (((size_t)t * DB + b) << 10) + tid * 4);
      ph[t][0] = b2f(pv.x); ph[t][1] = b2f(pv.y); ph[t][2] = b2f(pv.z); ph[t][3] = b2f(pv.w);
      p[t] = hv.x * ph[t][0] + hv.y * ph[t][1] + hv.z * ph[t][2] + hv.w * ph[t][3];
    }
#pragma unroll
    for (int t = 0; t < DT; ++t) {
#pragma unroll
      for (int off = 32; off; off >>= 1) p[t] += __shfl_xor(p[t], off);
      if (lane == 0) red[t][wid] = p[t];
    }
    __syncthreads();
    if (tid == 0) {
      float lg[DT];
      float mx = -1e30f;
#pragma unroll
      for (int t = 0; t < DT; ++t) {
        lg[t] = (red[t][0] + red[t][1] + red[t][2] + red[t][3]) * 0.03125f;
        mx = fmaxf(mx, lg[t]);
      }
      float s = 0.f;
#pragma unroll
      for (int t = 0; t < DT; ++t) { lg[t] = __expf(lg[t] - mx); s += lg[t]; }
      float inv = 1.f / s;
#pragma unroll
      for (int t = 0; t < DT; ++t) wgt[t] = lg[t] * inv;
    }
    __syncthreads();
    float4 a = make_float4(0, 0, 0, 0);
#pragma unroll
    for (int t = 0; t < DT; ++t) {
      const float w = wgt[t];
      a.x += w * ph[t][0]; a.y += w * ph[t][1]; a.z += w * ph[t][2]; a.w += w * ph[t][3];
    }
    store_b4(Zw, ((size_t)b << 11) + tid * 4, a);
  }

  if (do_cls) {
    __syncthreads();
    if (tid < DC)
      out[((size_t)b * DT + tprev) * DC + tid] =
          redc[tid][0] + redc[tid][1] + redc[tid][2] + redc[tid][3] + clsb[tid];
  }
}

extern "C" void kernel_launch(void* const* d_in, const int* in_sizes, int n_in,
                              void* d_out, int out_size, void* d_ws, size_t ws_size,
                              hipStream_t stream) {
  const float* x    = (const float*)d_in[0];
  const float* eWih = (const float*)d_in[1];
  const float* eWhh = (const float*)d_in[2];
  const float* ebih = (const float*)d_in[3];
  const float* ebhh = (const float*)d_in[4];
  const float* pW   = (const float*)d_in[5];
  const float* pb   = (const float*)d_in[6];
  const float* dWih = (const float*)d_in[7];
  const float* dWhh = (const float*)d_in[8];
  const float* dbih = (const float*)d_in[9];
  const float* dbhh = (const float*)d_in[10];
  const float* clsW = (const float*)d_in[11];
  const float* clsb = (const float*)d_in[12];
  float* out = (float*)d_out;

  char* p = (char*)d_ws;
  auto alloc = [&](size_t bytes) -> void* {
    char* r = p; p += (bytes + 255) & ~(size_t)255; return (void*)r;
  };
  u16* Xb    = (u16*)alloc((size_t)DB * DT * DF * 2);        // 54.5 MB (reused as projHb)
  u16* eWx   = (u16*)alloc((size_t)DG * 2048 * 2);           // 16.8
  u16* eWh   = (u16*)alloc((size_t)DG * 1024 * 2);           //  8.4
  u16* dWx   = (u16*)alloc((size_t)DG * 2048 * 2);           // 16.8
  u16* dWah  = (u16*)alloc((size_t)DG * 2048 * 2);           // 16.8
  u16* pWb   = (u16*)alloc((size_t)DH * DH * 2);             //  2.1
  u16* Hb    = (u16*)alloc((size_t)DT * DB * DH * 2);        // 27.3
  u16* encXg = (u16*)alloc((size_t)DB * DT * DG * 2);        // 109
  u16* decXg = (u16*)alloc((size_t)DB * DT * DG * 2);        // 109
  u16* Z0    = (u16*)alloc((size_t)DB * 2048 * 2);           //  2.1
  u16* Z1    = (u16*)alloc((size_t)DB * 2048 * 2);           //  2.1
  u16* Hz    = (u16*)alloc((size_t)DB * DH * 2);             //  1.0
  float* eCs = (float*)alloc((size_t)DB * DH * 4);           //  2.1
  float* dCs = (float*)alloc((size_t)DB * DH * 4);           //  2.1
  float* ebs = (float*)alloc(DG * 4);
  float* dbs = (float*)alloc(DG * 4);
  u16* projHb = Xb;                                          // alias: Xb dead after decXg
  // total ~371 MB (< ~436 MB ws)

  // ---- pack ----
  cvt4_kernel<<<2048, 256, 0, stream>>>(x, Xb, (int)((size_t)DB * DT * DF / 4));
  pack_perm_kernel<<<2048, 256, 0, stream>>>(eWih, DF, 0, DF / 4, eWx, 2048, 0);
  pack_perm_kernel<<<2048, 256, 0, stream>>>(eWhh, DH, 0, DH / 4, eWh, 1024, 0);
  pack_perm_kernel<<<2048, 256, 0, stream>>>(dWih, 3072, 0, DF / 4, dWx, 2048, 0);
  pack_perm_kernel<<<2048, 256, 0, stream>>>(dWih, 3072, 2048, DH / 4, dWah, 2048, 0);
  pack_perm_kernel<<<2048, 256, 0, stream>>>(dWhh, DH, 0, DH / 4, dWah, 2048, 1024);
  cvt4_kernel<<<1024, 256, 0, stream>>>(pW, pWb, DH * DH / 4);
  pack_bias_perm_kernel<<<16, 256, 0, stream>>>(ebih, ebhh, ebs);
  pack_bias_perm_kernel<<<16, 256, 0, stream>>>(dbih, dbhh, dbs);
  hipMemsetAsync(Hz, 0, (size_t)DB * DH * 2, stream);
  hipMemsetAsync(Z0, 0, (size_t)DB * 2048 * 2, stream);

  // ---- hoisted x-gate GEMMs (rows in (b*26+t) order), bf16 out, permuted cols ----
  gemm_bt<1><<<6656, 256, 0, stream>>>(
      Xb, DF, DF, Xb, DF, eWx, DF, ebs, encXg, DG, DB * DT, DG, DF);
  gemm_bt<1><<<6656, 256, 0, stream>>>(
      Xb, DF, DF, Xb, DF, dWx, DF, dbs, decXg, DG, DB * DT, DG, DF);

  // ---- encoder: fused gemm+cell per step ----
  for (int t = 0; t < DT; ++t) {
    step_gemm<0><<<256, 512, 0, stream>>>(
        (t == 0) ? Hz : (Hb + (size_t)(t - 1) * DB * DH), eWh,
        encXg + (size_t)t * DG, (long)DT * DG, eCs,
        Hb + (size_t)t * DB * DH, DH, t == 0);
  }

  // ---- projection of all encoder states (bf16 out; overwrites Xb region) ----
  gemm_bt<1><<<1664, 256, 0, stream>>>(
      Hb, DH, DH, Hb, DH, pWb, DH, pb, projHb, DH, DT * DB, DH, DH);

  // ---- decoder: attn(t)+cls(t-1), then fused gemm+cell ----
  for (int t = 0; t < DT; ++t) {
    u16* Zc = (t & 1) ? Z1 : Z0;
    u16* Zn = (t & 1) ? Z0 : Z1;
    attn_cls_kernel<1><<<DB, 256, 0, stream>>>(
        projHb, Zc, Zc, clsW, clsb, out, t > 0, t - 1);
    step_gemm<1><<<256, 512, 0, stream>>>(
        Zc, dWah, decXg + (size_t)t * DG, (long)DT * DG, dCs, Zn, 2048, t == 0);
  }
  // final classifier for h_25 (lives in Z0 after t=25)
  attn_cls_kernel<0><<<DB, 256, 0, stream>>>(
      projHb, Z0, Z0, clsW, clsb, out, 1, DT - 1);
}